// Round 1
// baseline (135.129 us; speedup 1.0000x reference)
//
#include <hip/hip_runtime.h>

#define D_MODEL 256
#define TX 512
#define TM 512
#define NB 4   // x-rows per block in fused kernel (must be 4: one wave per row)

__device__ __forceinline__ float fexp2(float x) { return __builtin_amdgcn_exp2f(x); }
__device__ __forceinline__ float frcp(float x)  { return __builtin_amdgcn_rcpf(x); }

// C[r][n] = (sum_k A[r][k]*W[n][k] + bias[n]) * 2*log2(e)
// M = 2048, N = K = 256. Grid (32, 4), block 256.
__global__ __launch_bounds__(256) void gemm_nt_scale(
    const float* __restrict__ A,
    const float* __restrict__ W,
    const float* __restrict__ bias,
    float* __restrict__ C)
{
    const float C_SCALE = 2.8853900817779268f; // 2*log2(e)
    __shared__ float As[16][68];
    __shared__ float Ws[16][68];
    const int tid = threadIdx.x;
    const int tx = tid & 15, ty = tid >> 4;
    const int rl = tid >> 2, g = tid & 3;
    const int r0 = blockIdx.x * 64, n0 = blockIdx.y * 64;
    float acc[4][4] = {};
    const float* Ap = A + (size_t)(r0 + rl) * 256 + g * 4;
    const float* Wp = W + (size_t)(n0 + rl) * 256 + g * 4;
    for (int k0 = 0; k0 < 256; k0 += 16) {
        float4 a4 = *(const float4*)(Ap + k0);
        float4 w4 = *(const float4*)(Wp + k0);
        __syncthreads();
        As[g*4+0][rl] = a4.x; As[g*4+1][rl] = a4.y;
        As[g*4+2][rl] = a4.z; As[g*4+3][rl] = a4.w;
        Ws[g*4+0][rl] = w4.x; Ws[g*4+1][rl] = w4.y;
        Ws[g*4+2][rl] = w4.z; Ws[g*4+3][rl] = w4.w;
        __syncthreads();
        #pragma unroll
        for (int kk = 0; kk < 16; ++kk) {
            float4 av = *(const float4*)&As[kk][ty*4];
            float4 wv = *(const float4*)&Ws[kk][tx*4];
            float a_[4] = {av.x, av.y, av.z, av.w};
            float w_[4] = {wv.x, wv.y, wv.z, wv.w};
            #pragma unroll
            for (int i = 0; i < 4; ++i)
                #pragma unroll
                for (int j = 0; j < 4; ++j)
                    acc[i][j] = fmaf(a_[i], w_[j], acc[i][j]);
        }
    }
    #pragma unroll
    for (int i = 0; i < 4; ++i) {
        const int r = r0 + ty*4 + i;
        #pragma unroll
        for (int j = 0; j < 4; ++j) {
            const int n = n0 + tx*4 + j;
            float v = acc[i][j];
            if (bias) v += bias[n];
            C[(size_t)r*256 + n] = v * C_SCALE;
        }
    }
}

// Fused: scores = W - 2*sum_d w[d]/(1+exp2(i1s+i2s)), mask, softmax, PV.
// Grid 512 (= B*TX/NB), block 256. Wave w handles x-row w for softmax/PV.
__global__ __launch_bounds__(256) void fused_tanh_attn(
    const float* __restrict__ I1s,    // [B*TX, D] pre-scaled by 2log2e
    const float* __restrict__ I2s,    // [B*TM, D] pre-scaled
    const float* __restrict__ memory, // [B, TM, D]
    const int*   __restrict__ mask,   // [B, TM]
    const float* __restrict__ wst,    // [D]
    float* __restrict__ out,          // [B*TX, D]
    float* __restrict__ Sout)         // [B*TX, TM]
{
    const float LOG2E = 1.4426950408889634f;
    const int t = threadIdx.x;
    const int blk = blockIdx.x;
    const int b = blk >> 7;                // TX/NB = 128 blocks per batch
    const int x0 = (blk & 127) * NB;
    const int wave = t >> 6, lane = t & 63;

    __shared__ float i1[NB][D_MODEL];
    __shared__ float wsh[D_MODEL];
    __shared__ float P[NB][TM];
    __shared__ float mneg[TM];
    __shared__ float wpart[4];

    // stage I1s rows, wst, mask
    const float* i1g = I1s + ((size_t)b * TX + x0) * D_MODEL;
    #pragma unroll
    for (int x = 0; x < NB; ++x) i1[x][t] = i1g[x * D_MODEL + t];
    const float wv = wst[t];
    wsh[t] = wv;
    mneg[t]       = mask[b*TM + t]       ? 0.f : -__builtin_inff();
    mneg[t + 256] = mask[b*TM + t + 256] ? 0.f : -__builtin_inff();

    // Wsum = sum(wst)
    float s = wv;
    #pragma unroll
    for (int off = 32; off > 0; off >>= 1) s += __shfl_xor(s, off);
    if (lane == 0) wpart[wave] = s;
    __syncthreads();
    const float Wsum = wpart[0] + wpart[1] + wpart[2] + wpart[3];

    // main: thread t owns m = t and m = t+256
    const float* i2a = I2s + ((size_t)b * TM + t) * D_MODEL;
    const float* i2b = i2a + 256 * D_MODEL;

    float acc[NB][2] = {};
    for (int d = 0; d < D_MODEL; d += 4) {
        float4 A4 = *(const float4*)(i2a + d);
        float4 B4 = *(const float4*)(i2b + d);
        float4 w4 = *(const float4*)&wsh[d];
        #pragma unroll
        for (int x = 0; x < NB; ++x) {
            float4 i14 = *(const float4*)&i1[x][d];
            acc[x][0] += w4.x * frcp(1.f + fexp2(i14.x + A4.x));
            acc[x][0] += w4.y * frcp(1.f + fexp2(i14.y + A4.y));
            acc[x][0] += w4.z * frcp(1.f + fexp2(i14.z + A4.z));
            acc[x][0] += w4.w * frcp(1.f + fexp2(i14.w + A4.w));
            acc[x][1] += w4.x * frcp(1.f + fexp2(i14.x + B4.x));
            acc[x][1] += w4.y * frcp(1.f + fexp2(i14.y + B4.y));
            acc[x][1] += w4.z * frcp(1.f + fexp2(i14.z + B4.z));
            acc[x][1] += w4.w * frcp(1.f + fexp2(i14.w + B4.w));
        }
    }

    // scores (pre-softmax) with mask
    #pragma unroll
    for (int x = 0; x < NB; ++x) {
        P[x][t]       = Wsum - 2.f * acc[x][0] + mneg[t];
        P[x][t + 256] = Wsum - 2.f * acc[x][1] + mneg[t + 256];
    }
    __syncthreads();

    // softmax: wave handles row x = wave; 8 values per lane
    {
        const int x = wave;
        float4 u0 = *(const float4*)&P[x][lane * 8];
        float4 u1 = *(const float4*)&P[x][lane * 8 + 4];
        float v[8] = {u0.x,u0.y,u0.z,u0.w,u1.x,u1.y,u1.z,u1.w};
        float mx = v[0];
        #pragma unroll
        for (int q = 1; q < 8; ++q) mx = fmaxf(mx, v[q]);
        #pragma unroll
        for (int off = 32; off > 0; off >>= 1) mx = fmaxf(mx, __shfl_xor(mx, off));
        float e[8];
        float sum = 0.f;
        #pragma unroll
        for (int q = 0; q < 8; ++q) { e[q] = fexp2((v[q] - mx) * LOG2E); sum += e[q]; }
        #pragma unroll
        for (int off = 32; off > 0; off >>= 1) sum += __shfl_xor(sum, off);
        const float inv = frcp(sum);
        float4 p0 = {e[0]*inv, e[1]*inv, e[2]*inv, e[3]*inv};
        float4 p1 = {e[4]*inv, e[5]*inv, e[6]*inv, e[7]*inv};
        *(float4*)&P[x][lane*8]   = p0;
        *(float4*)&P[x][lane*8+4] = p1;
        float* Sg = Sout + ((size_t)b*TX + x0 + x) * TM + lane*8;
        *(float4*)Sg     = p0;
        *(float4*)(Sg+4) = p1;
    }
    __syncthreads();

    // PV: wave handles row x = wave; lane covers d = 4*lane..4*lane+3
    {
        const int x = wave;
        const float* mem = memory + (size_t)b * TM * D_MODEL + lane * 4;
        float4 o = {0.f, 0.f, 0.f, 0.f};
        #pragma unroll 4
        for (int m = 0; m < TM; ++m) {
            const float p = P[x][m];
            float4 mv = *(const float4*)(mem + (size_t)m * D_MODEL);
            o.x = fmaf(p, mv.x, o.x);
            o.y = fmaf(p, mv.y, o.y);
            o.z = fmaf(p, mv.z, o.z);
            o.w = fmaf(p, mv.w, o.w);
        }
        float* og = out + ((size_t)b*TX + x0 + x) * D_MODEL + lane*4;
        *(float4*)og = o;
    }
}

extern "C" void kernel_launch(void* const* d_in, const int* in_sizes, int n_in,
                              void* d_out, int out_size, void* d_ws, size_t ws_size,
                              hipStream_t stream) {
    const float* x    = (const float*)d_in[0];
    const float* mem  = (const float*)d_in[1];
    const int*   mask = (const int*)d_in[2];
    const float* w1   = (const float*)d_in[3];
    const float* b1   = (const float*)d_in[4];
    const float* w2   = (const float*)d_in[5];
    const float* wst  = (const float*)d_in[6];

    float* out  = (float*)d_out;                  // [4*512*256]
    float* Sout = out + 4 * 512 * 256;            // [4*512*512]
    float* I1s  = (float*)d_ws;                   // 524288 floats (2 MB)
    float* I2s  = I1s + 4 * 512 * 256;            // 524288 floats (2 MB)

    dim3 gg(2048 / 64, 256 / 64);
    gemm_nt_scale<<<gg, 256, 0, stream>>>(x,   w1, b1,      I1s);
    gemm_nt_scale<<<gg, 256, 0, stream>>>(mem, w2, nullptr, I2s);
    fused_tanh_attn<<<512, 256, 0, stream>>>(I1s, I2s, mem, mask, wst, out, Sout);
}